// Round 6
// baseline (659.935 us; speedup 1.0000x reference)
//
#include <hip/hip_runtime.h>
#include <hip/hip_bf16.h>

#define BB 64
#define TT 2048
#define DD 256
#define EPSF 1e-7f
#define ROWS 32         // rows per block
#define BPB 64          // blocks per batch-row (TT/ROWS)
#define XS_STRIDE 264   // shorts/row: 528 B = 33*16 B -> 16B-aligned b128 reads

typedef __attribute__((ext_vector_type(8))) short v8s;   // 8 x bf16 (4 VGPRs) — MFMA A/B frag
typedef __attribute__((ext_vector_type(4))) float v4f;   // MFMA C/D frag

__device__ __forceinline__ float bf2f(unsigned short u) {
    union { unsigned int i; float f; } c;
    c.i = ((unsigned int)u) << 16;
    return c.f;
}

__device__ __forceinline__ unsigned int pack2_bf16(float a, float b) {
    union { __hip_bfloat162 h; unsigned int u; } c;
    c.h = __float22bfloat162_rn(make_float2(a, b));   // v_cvt_pk_bf16_f32, RNE
    return c.u;
}

__device__ __forceinline__ unsigned short f2bf_rn(float f) {
    union { __hip_bfloat16 h; unsigned short u; } c;
    c.h = __float2bfloat16(f);
    return c.u;
}

// ---------------- kernel 1: W -> frag-order bf16 Wt + (2*bias, uw) pairs ---------------------
// Wt[(((nt*8 + ks)*16 + m)*4 + quad)*8 + j] = bf16(W[k][n]), n = nt*16+m, k = quad*8+ks*32+j.
// For each (nt,ks) the 64 lanes (quad,m) read one CONTIGUOUS 1 KB segment (coalesced).
__global__ __launch_bounds__(256) void pack_wt_frag(const float* __restrict__ W,
                                                    const float* __restrict__ bias,
                                                    const float* __restrict__ uw,
                                                    unsigned short* __restrict__ Wt,
                                                    float2* __restrict__ buv) {
    int idx = blockIdx.x * 256 + threadIdx.x;   // 0..65535
    int j    = idx & 7;
    int quad = (idx >> 3) & 3;
    int m    = (idx >> 5) & 15;
    int ks   = (idx >> 9) & 7;
    int nt   = idx >> 12;
    int n = nt * 16 + m;
    int k = quad * 8 + ks * 32 + j;
    Wt[idx] = f2bf_rn(W[(size_t)k * DD + n]);
    if (blockIdx.x == 0)
        buv[threadIdx.x] = make_float2(2.0f * bias[threadIdx.x], uw[threadIdx.x]);
}

// ---------------- kernel 2: fused (R3 structure) + atomic epilogue (finalize folded in) -----
// Block = 32 rows, 4 waves. Wave w computes partial e over nt = w*4..w*4+3 for ALL 32 rows
// (2 m-tiles cached in regs), B dbuf from frag-order Wt (coalesced). After num merge, blocks
// atomicAdd into per-b accumulators; the LAST of 64 blocks per b writes out = num/(den+EPS).
// Activation: tanh(y)*uw = uw*(1 - 2*rcp(exp(2*acc + 2*bias)+1)) — 7 VALU ops/elem via v_rcp.
__global__ __launch_bounds__(256, 6) void fused_att8(const float* __restrict__ x,
                                                     const unsigned short* __restrict__ Wt,
                                                     const float2* __restrict__ buv,
                                                     const int* __restrict__ mask,
                                                     float* __restrict__ numacc,
                                                     float* __restrict__ denacc,
                                                     int* __restrict__ done,
                                                     float* __restrict__ out) {
    __shared__ unsigned short xs[ROWS * XS_STRIDE];   // 16896 B
    __shared__ float ered[4][ROWS];                   // per-wave e partials
    __shared__ float red[4][DD];                      // num merge
    __shared__ int lastf;

    const int tid  = threadIdx.x;
    const int w    = tid >> 6;     // wave 0..3
    const int lane = tid & 63;
    const int quad = lane >> 4;    // 0..3
    const int m    = lane & 15;    // 0..15
    const long R0  = (long)blockIdx.x * ROWS;   // block's first row (global, b*TT + t)
    const long Rw  = R0 + w * 8;                // this wave's staging rows
    const int  bb  = blockIdx.x >> 6;           // batch row 0..63

    // per-lane base into frag-ordered Wt: fragment slot (m*4+quad)*8 shorts
    const size_t blane = (size_t)((m * 4 + quad) * 8);

    // hoisted (2*bias, uw) for this wave's nt range (n = (w*4+i)*16 + m)
    float bias2_r[4], uw_r[4];
#pragma unroll
    for (int i = 0; i < 4; ++i) {
        float2 bu = buv[(w * 4 + i) * 16 + m];
        bias2_r[i] = bu.x;
        uw_r[i]    = bu.y;
    }

    // ---- stage this wave's 8 rows into its LDS slice (1 KB coalesced per load)
    {
        const float* gp = x + Rw * DD + lane * 4;
        unsigned short* sp = xs + (size_t)(w * 8) * XS_STRIDE + lane * 4;
#pragma unroll
        for (int r = 0; r < 8; ++r) {
            float4 v = *(const float4*)(gp + (size_t)r * DD);
            uint2 pp = make_uint2(pack2_bf16(v.x, v.y), pack2_bf16(v.z, v.w));
            *(uint2*)(sp + (size_t)r * XS_STRIDE) = pp;
        }
    }
    __syncthreads();

    // ---- e-GEMM: A (2 m-tiles) cached in regs, B double-buffered over this wave's 4 nt
    float esum[2][4];
#pragma unroll
    for (int mt = 0; mt < 2; ++mt)
#pragma unroll
        for (int r = 0; r < 4; ++r) esum[mt][r] = 0.f;

    v8s a0[8], a1[8];
    {
        const unsigned short* ap0 = xs + (size_t)m * XS_STRIDE + quad * 8;
#pragma unroll
        for (int ks = 0; ks < 8; ++ks) {
            a0[ks] = *(const v8s*)(ap0 + ks * 32);
            a1[ks] = *(const v8s*)(ap0 + 16 * XS_STRIDE + ks * 32);
        }
    }
    v8s bbuf[2][8];
    {
        const unsigned short* bp = Wt + (size_t)(w * 4) * 4096 + blane;
#pragma unroll
        for (int ks = 0; ks < 8; ++ks) bbuf[0][ks] = *(const v8s*)(bp + ks * 512);
    }
#pragma unroll
    for (int i = 0; i < 4; ++i) {
        const int cur = i & 1;
        if (i < 3) {   // prefetch next nt's B while computing on current (coalesced 1KB loads)
            const unsigned short* bp = Wt + (size_t)(w * 4 + i + 1) * 4096 + blane;
#pragma unroll
            for (int ks = 0; ks < 8; ++ks) bbuf[cur ^ 1][ks] = *(const v8s*)(bp + ks * 512);
        }
        v4f acc0 = {0.f, 0.f, 0.f, 0.f};
        v4f acc1 = {0.f, 0.f, 0.f, 0.f};
#pragma unroll
        for (int ks = 0; ks < 8; ++ks) {
            acc0 = __builtin_amdgcn_mfma_f32_16x16x32_bf16(a0[ks], bbuf[cur][ks], acc0, 0, 0, 0);
            acc1 = __builtin_amdgcn_mfma_f32_16x16x32_bf16(a1[ks], bbuf[cur][ks], acc1, 0, 0, 0);
        }
        // tanh(acc+bias)*uw = uw*(1 - 2*rcp(exp(2*acc + 2*bias) + 1))
#pragma unroll
        for (int r = 0; r < 4; ++r) {
            float r0 = __builtin_amdgcn_rcpf(__expf(__builtin_fmaf(acc0[r], 2.0f, bias2_r[i])) + 1.0f);
            float r1 = __builtin_amdgcn_rcpf(__expf(__builtin_fmaf(acc1[r], 2.0f, bias2_r[i])) + 1.0f);
            esum[0][r] = __builtin_fmaf(uw_r[i], __builtin_fmaf(-2.0f, r0, 1.0f), esum[0][r]);
            esum[1][r] = __builtin_fmaf(uw_r[i], __builtin_fmaf(-2.0f, r1, 1.0f), esum[1][r]);
        }
    }

    // ---- reduce over 16 n-lanes; m==0 lanes write this wave's e-partials for all 32 rows
#pragma unroll
    for (int o = 1; o < 16; o <<= 1)
#pragma unroll
        for (int mt = 0; mt < 2; ++mt)
#pragma unroll
            for (int r = 0; r < 4; ++r)
                esum[mt][r] += __shfl_xor(esum[mt][r], o, 64);
    if (m == 0) {
#pragma unroll
        for (int mt = 0; mt < 2; ++mt)
#pragma unroll
            for (int r = 0; r < 4; ++r)
                ered[w][mt * 16 + quad * 4 + r] = esum[mt][r];
    }
    __syncthreads();

    // ---- p for all 32 rows (identical in all waves); den = sum over the 32 rows
    const int rl = lane & 31;
    float et = ered[0][rl] + ered[1][rl] + ered[2][rl] + ered[3][rl];
    float p_loc = __expf(et) * (float)mask[R0 + rl];
    float den = p_loc;
#pragma unroll
    for (int o = 1; o < 32; o <<= 1) den += __shfl_xor(den, o, 64);

    // this wave's own 8 rows' p via shuffles (source lanes 0..31)
    float p_all[8];
#pragma unroll
    for (int t = 0; t < 8; ++t) p_all[t] = __shfl(p_loc, w * 8 + t, 64);

    // ---- weighted sum over own 8 rows from own LDS slice; lane covers d = lane*4..+3
    float num[4] = {0.f, 0.f, 0.f, 0.f};
    {
        const unsigned short* xp = xs + (size_t)(w * 8) * XS_STRIDE + lane * 4;
#pragma unroll
        for (int t = 0; t < 8; ++t) {
            uint2 xv = *(const uint2*)(xp + (size_t)t * XS_STRIDE);
            float pt = p_all[t];
            num[0] += pt * bf2f((unsigned short)(xv.x & 0xffffu));
            num[1] += pt * bf2f((unsigned short)(xv.x >> 16));
            num[2] += pt * bf2f((unsigned short)(xv.y & 0xffffu));
            num[3] += pt * bf2f((unsigned short)(xv.y >> 16));
        }
    }

    // ---- merge 4 wave-partials; atomic-accumulate into per-b accumulators
    *(float4*)&red[w][lane * 4] = make_float4(num[0], num[1], num[2], num[3]);
    __syncthreads();
    float s = red[0][tid] + red[1][tid] + red[2][tid] + red[3][tid];
    atomicAdd(&numacc[(size_t)bb * DD + tid], s);
    if (tid == 0) atomicAdd(&denacc[bb], den);
    __threadfence();                 // make this block's adds device-visible before the inc
    __syncthreads();
    if (tid == 0) {
        int old = atomicAdd(&done[bb], 1);
        lastf = (old == BPB - 1);
    }
    __syncthreads();
    if (lastf) {                     // last block for this b: finalize out[b][:]
        float dsum = __hip_atomic_load(&denacc[bb], __ATOMIC_RELAXED, __HIP_MEMORY_SCOPE_AGENT);
        float nsum = __hip_atomic_load(&numacc[(size_t)bb * DD + tid],
                                       __ATOMIC_RELAXED, __HIP_MEMORY_SCOPE_AGENT);
        out[(size_t)bb * DD + tid] = nsum / (dsum + EPSF);
    }
}

extern "C" void kernel_launch(void* const* d_in, const int* in_sizes, int n_in,
                              void* d_out, int out_size, void* d_ws, size_t ws_size,
                              hipStream_t stream) {
    const float* x    = (const float*)d_in[0];  // [64,2048,256] fp32
    const float* W    = (const float*)d_in[1];  // [256,256] fp32
    const float* bias = (const float*)d_in[2];  // [256] fp32
    const float* uw   = (const float*)d_in[3];  // [256] fp32
    const int*   mask = (const int*)d_in[4];    // [64,2048] int32
    float*       out  = (float*)d_out;          // [64,256] fp32

    char* ws = (char*)d_ws;
    unsigned short* Wt = (unsigned short*)ws;            // 128 KB bf16 W in frag order
    float2* buv        = (float2*)(ws + 131072);         // 2 KB (2*bias, uw)
    float* numacc      = (float*)(ws + 133120);          // 64*256*4 = 65536 B
    float* denacc      = (float*)(ws + 198656);          // 256 B
    int*   done        = (int*)(ws + 198912);            // 256 B

    // zero the accumulators (capturable async memset; re-runs on every graph replay)
    hipMemsetAsync(ws + 133120, 0, 65536 + 256 + 256, stream);

    pack_wt_frag<<<dim3(256), dim3(256), 0, stream>>>(W, bias, uw, Wt, buv);
    fused_att8<<<dim3(4096), dim3(256), 0, stream>>>(x, Wt, buv, mask,
                                                     numacc, denacc, done, out);
}

// Round 8
// 213.055 us; speedup vs baseline: 3.0975x; 3.0975x over previous
//
#include <hip/hip_runtime.h>
#include <hip/hip_bf16.h>

#define BB 64
#define TT 2048
#define DD 256
#define EPSF 1e-7f
#define ROWS 32                 // rows per chunk
#define CHUNKS 4                // chunks per block
#define BLKROWS (ROWS * CHUNKS) // 128 rows per block
#define XS_STRIDE 264           // shorts/row: 528 B = 33*16 B -> 16B-aligned b128 reads

typedef __attribute__((ext_vector_type(8))) short v8s;   // 8 x bf16 (4 VGPRs) — MFMA A/B frag
typedef __attribute__((ext_vector_type(4))) float v4f;   // MFMA C/D frag

__device__ __forceinline__ float bf2f(unsigned short u) {
    union { unsigned int i; float f; } c;
    c.i = ((unsigned int)u) << 16;
    return c.f;
}

__device__ __forceinline__ unsigned int pack2_bf16(float a, float b) {
    union { __hip_bfloat162 h; unsigned int u; } c;
    c.h = __float22bfloat162_rn(make_float2(a, b));   // v_cvt_pk_bf16_f32, RNE
    return c.u;
}

__device__ __forceinline__ unsigned short f2bf_rn(float f) {
    union { __hip_bfloat16 h; unsigned short u; } c;
    c.h = __float2bfloat16(f);
    return c.u;
}

// ---------------- kernel 1: W -> frag-order bf16 Wt + (2*bias, uw) pairs ---------------------
// Wt[(((nt*8 + ks)*16 + m)*4 + quad)*8 + j] = bf16(W[k][n]), n = nt*16+m, k = quad*8+ks*32+j.
// For each (nt,ks) the 64 lanes (quad,m) read one CONTIGUOUS 1 KB segment (coalesced).
__global__ __launch_bounds__(256) void pack_wt_frag(const float* __restrict__ W,
                                                    const float* __restrict__ bias,
                                                    const float* __restrict__ uw,
                                                    unsigned short* __restrict__ Wt,
                                                    float2* __restrict__ buv) {
    int idx = blockIdx.x * 256 + threadIdx.x;   // 0..65535
    int j    = idx & 7;
    int quad = (idx >> 3) & 3;
    int m    = (idx >> 5) & 15;
    int ks   = (idx >> 9) & 7;
    int nt   = idx >> 12;
    int n = nt * 16 + m;
    int k = quad * 8 + ks * 32 + j;
    Wt[idx] = f2bf_rn(W[(size_t)k * DD + n]);
    if (blockIdx.x == 0)
        buv[threadIdx.x] = make_float2(2.0f * bias[threadIdx.x], uw[threadIdx.x]);
}

// ---------------- kernel 2: R3 inner structure + B-resident 4-chunk persistence --------------
// Block = 128 rows as 4 chunks of 32; 4 waves, nt-split (wave w owns nt = w*4..w*4+3).
// Wave's FULL B slice (4 nt = 32 KB = 128 VGPR) loaded ONCE, reused by all 4 chunks -> Wt
// L2 traffic drops 4x vs R3. Per chunk: stage own 8 rows -> LDS(dbuf), barrier, 2-mtile GEMM
// from reg-B, rcp-tanh epilogue, 16-lane reduce, barrier, p/den/num (num,den acc across chunks).
__global__ __launch_bounds__(256, 2) void fused_att9(const float* __restrict__ x,
                                                     const unsigned short* __restrict__ Wt,
                                                     const float2* __restrict__ buv,
                                                     const int* __restrict__ mask,
                                                     float* __restrict__ numpart,
                                                     float* __restrict__ denpart) {
    __shared__ unsigned short xs[2 * ROWS * XS_STRIDE];  // 33792 B double buffer
    __shared__ float ered[4][ROWS];                      // per-wave e partials
    __shared__ float red[4][DD];                         // num merge

    const int tid  = threadIdx.x;
    const int w    = tid >> 6;     // wave 0..3
    const int lane = tid & 63;
    const int quad = lane >> 4;    // 0..3
    const int m    = lane & 15;    // 0..15
    const long R0  = (long)blockIdx.x * BLKROWS;   // block's first row

    // per-lane base into frag-ordered Wt: fragment slot (m*4+quad)*8 shorts
    const size_t blane = (size_t)((m * 4 + quad) * 8);

    // hoisted (2*bias, uw) for this wave's nt range (n = (w*4+i)*16 + m)
    float bias2_r[4], uw_r[4];
#pragma unroll
    for (int i = 0; i < 4; ++i) {
        float2 bu = buv[(w * 4 + i) * 16 + m];
        bias2_r[i] = bu.x;
        uw_r[i]    = bu.y;
    }

    // ---- stage chunk 0 (wave's 8 rows) into LDS buf0
    {
        const float* gp = x + (R0 + (size_t)w * 8) * DD + lane * 4;
        unsigned short* sp = xs + (size_t)(w * 8) * XS_STRIDE + lane * 4;
        float4 vr[8];
#pragma unroll
        for (int r = 0; r < 8; ++r) vr[r] = *(const float4*)(gp + (size_t)r * DD);
#pragma unroll
        for (int r = 0; r < 8; ++r) {
            uint2 pp = make_uint2(pack2_bf16(vr[r].x, vr[r].y), pack2_bf16(vr[r].z, vr[r].w));
            *(uint2*)(sp + (size_t)r * XS_STRIDE) = pp;
        }
    }

    // ---- load this wave's FULL B slice once: 4 nt x 8 ks, 32 coalesced 1 KB loads, 128 VGPR
    v8s breg[4][8];
#pragma unroll
    for (int i = 0; i < 4; ++i) {
        const unsigned short* bp = Wt + (size_t)(w * 4 + i) * 4096 + blane;
#pragma unroll
        for (int ks = 0; ks < 8; ++ks) breg[i][ks] = *(const v8s*)(bp + ks * 512);
    }

    float num[4] = {0.f, 0.f, 0.f, 0.f};   // accumulated across chunks
    float denacc = 0.f;

    for (int c = 0; c < CHUNKS; ++c) {
        unsigned short* xb = xs + (size_t)(c & 1) * (ROWS * XS_STRIDE);

        // ---- stage chunk c (c>0); chunk c-1's num read the OTHER buffer (safe by ordering)
        if (c > 0) {
            const float* gp = x + (R0 + (size_t)c * ROWS + (size_t)w * 8) * DD + lane * 4;
            unsigned short* sp = xb + (size_t)(w * 8) * XS_STRIDE + lane * 4;
            float4 vr[8];
#pragma unroll
            for (int r = 0; r < 8; ++r) vr[r] = *(const float4*)(gp + (size_t)r * DD);
#pragma unroll
            for (int r = 0; r < 8; ++r) {
                uint2 pp = make_uint2(pack2_bf16(vr[r].x, vr[r].y), pack2_bf16(vr[r].z, vr[r].w));
                *(uint2*)(sp + (size_t)r * XS_STRIDE) = pp;
            }
        }
        __syncthreads();   // barrier 1: xb staged

        // ---- A fragments for block-rows m and m+16 of this chunk (16 ds_read_b128)
        v8s a0[8], a1[8];
        {
            const unsigned short* ap0 = xb + (size_t)m * XS_STRIDE + quad * 8;
#pragma unroll
            for (int ks = 0; ks < 8; ++ks) {
                a0[ks] = *(const v8s*)(ap0 + ks * 32);
                a1[ks] = *(const v8s*)(ap0 + 16 * XS_STRIDE + ks * 32);
            }
        }

        float esum[2][4];
#pragma unroll
        for (int mt = 0; mt < 2; ++mt)
#pragma unroll
            for (int r = 0; r < 4; ++r) esum[mt][r] = 0.f;

#pragma unroll
        for (int i = 0; i < 4; ++i) {
            v4f acc0 = {0.f, 0.f, 0.f, 0.f};
            v4f acc1 = {0.f, 0.f, 0.f, 0.f};
#pragma unroll
            for (int ks = 0; ks < 8; ++ks) {
                acc0 = __builtin_amdgcn_mfma_f32_16x16x32_bf16(a0[ks], breg[i][ks], acc0, 0, 0, 0);
                acc1 = __builtin_amdgcn_mfma_f32_16x16x32_bf16(a1[ks], breg[i][ks], acc1, 0, 0, 0);
            }
            // tanh(acc+bias)*uw = uw*(1 - 2*rcp(exp(2*acc + 2*bias) + 1))
#pragma unroll
            for (int r = 0; r < 4; ++r) {
                float r0 = __builtin_amdgcn_rcpf(__expf(__builtin_fmaf(acc0[r], 2.0f, bias2_r[i])) + 1.0f);
                float r1 = __builtin_amdgcn_rcpf(__expf(__builtin_fmaf(acc1[r], 2.0f, bias2_r[i])) + 1.0f);
                esum[0][r] = __builtin_fmaf(uw_r[i], __builtin_fmaf(-2.0f, r0, 1.0f), esum[0][r]);
                esum[1][r] = __builtin_fmaf(uw_r[i], __builtin_fmaf(-2.0f, r1, 1.0f), esum[1][r]);
            }
        }

        // ---- reduce over 16 n-lanes; m==0 lanes write this wave's e-partials for 32 rows
#pragma unroll
        for (int o = 1; o < 16; o <<= 1)
#pragma unroll
            for (int mt = 0; mt < 2; ++mt)
#pragma unroll
                for (int r = 0; r < 4; ++r)
                    esum[mt][r] += __shfl_xor(esum[mt][r], o, 64);
        if (m == 0) {
#pragma unroll
            for (int mt = 0; mt < 2; ++mt)
#pragma unroll
                for (int r = 0; r < 4; ++r)
                    ered[w][mt * 16 + quad * 4 + r] = esum[mt][r];
        }
        __syncthreads();   // barrier 2: ered ready

        // ---- p for all 32 rows (identical in all waves); den accumulate
        const int rl = lane & 31;
        float et = ered[0][rl] + ered[1][rl] + ered[2][rl] + ered[3][rl];
        float p_loc = __expf(et) * (float)mask[R0 + (size_t)c * ROWS + rl];
        float den = p_loc;
#pragma unroll
        for (int o = 1; o < 32; o <<= 1) den += __shfl_xor(den, o, 64);
        denacc += den;

        float p_all[8];
#pragma unroll
        for (int t = 0; t < 8; ++t) p_all[t] = __shfl(p_loc, w * 8 + t, 64);

        // ---- accumulate weighted sum over own 8 rows from LDS; lane covers d = lane*4..+3
        {
            const unsigned short* xp = xb + (size_t)(w * 8) * XS_STRIDE + lane * 4;
#pragma unroll
            for (int t = 0; t < 8; ++t) {
                uint2 xv = *(const uint2*)(xp + (size_t)t * XS_STRIDE);
                float pt = p_all[t];
                num[0] += pt * bf2f((unsigned short)(xv.x & 0xffffu));
                num[1] += pt * bf2f((unsigned short)(xv.x >> 16));
                num[2] += pt * bf2f((unsigned short)(xv.y & 0xffffu));
                num[3] += pt * bf2f((unsigned short)(xv.y >> 16));
            }
        }
    }

    // ---- epilogue: merge 4 wave-partials once, single store per block
    *(float4*)&red[w][lane * 4] = make_float4(num[0], num[1], num[2], num[3]);
    __syncthreads();
    float s = red[0][tid] + red[1][tid] + red[2][tid] + red[3][tid];
    numpart[(size_t)blockIdx.x * DD + tid] = s;
    if (tid == 0) denpart[blockIdx.x] = denacc;   // wave 0's denacc covers all 128 rows
}

// ---------------- kernel 3: out[b][d] = sum_c num[b*16+c][d] / (sum_c den[b*16+c] + EPS) ------
__global__ __launch_bounds__(256) void finalize(const float* __restrict__ numpart,
                                                const float* __restrict__ denpart,
                                                float* __restrict__ out) {
    __shared__ float4 part[4][64];
    int b = blockIdx.x, t = threadIdx.x;
    int d4 = t & 63;        // float4 index over 256 d
    int cq = t >> 6;        // chunk quarter (4 chunks each)
    float4 s = make_float4(0.f, 0.f, 0.f, 0.f);
    const float* np = numpart + ((size_t)b * 16 + (size_t)cq * 4) * DD + d4 * 4;
#pragma unroll
    for (int c = 0; c < 4; ++c) {
        float4 v = *(const float4*)(np + (size_t)c * DD);
        s.x += v.x; s.y += v.y; s.z += v.z; s.w += v.w;
    }
    part[cq][d4] = s;
    float dp = denpart[b * 16 + (t & 15)];
    __syncthreads();
    if (t < 64) {   // wave 0: each 16-lane group holds all 16 den partials -> reduce in group
#pragma unroll
        for (int o = 1; o < 16; o <<= 1) dp += __shfl_xor(dp, o, 64);
        float4 p0 = part[0][t], p1 = part[1][t], p2 = part[2][t], p3 = part[3][t];
        float inv = 1.0f / (dp + EPSF);
        float4 r;
        r.x = (p0.x + p1.x + p2.x + p3.x) * inv;
        r.y = (p0.y + p1.y + p2.y + p3.y) * inv;
        r.z = (p0.z + p1.z + p2.z + p3.z) * inv;
        r.w = (p0.w + p1.w + p2.w + p3.w) * inv;
        *(float4*)(out + (size_t)b * DD + t * 4) = r;
    }
}

extern "C" void kernel_launch(void* const* d_in, const int* in_sizes, int n_in,
                              void* d_out, int out_size, void* d_ws, size_t ws_size,
                              hipStream_t stream) {
    const float* x    = (const float*)d_in[0];  // [64,2048,256] fp32
    const float* W    = (const float*)d_in[1];  // [256,256] fp32
    const float* bias = (const float*)d_in[2];  // [256] fp32
    const float* uw   = (const float*)d_in[3];  // [256] fp32
    const int*   mask = (const int*)d_in[4];    // [64,2048] int32
    float*       out  = (float*)d_out;          // [64,256] fp32

    char* ws = (char*)d_ws;
    unsigned short* Wt = (unsigned short*)ws;                 // 128 KB bf16 W in frag order
    float2* buv        = (float2*)(ws + 131072);              // 2 KB (2*bias, uw)
    float* numpart     = (float*)(ws + 133120);               // 1024*256*4 = 1 MB
    float* denpart     = (float*)(ws + 133120 + 1048576);     // 4 KB

    pack_wt_frag<<<dim3(256), dim3(256), 0, stream>>>(W, bias, uw, Wt, buv);
    fused_att9<<<dim3(1024), dim3(256), 0, stream>>>(x, Wt, buv, mask, numpart, denpart);
    finalize<<<dim3(64), dim3(256), 0, stream>>>(numpart, denpart, out);
}